// Round 1
// baseline (1911.519 us; speedup 1.0000x reference)
//
#include <hip/hip_runtime.h>

// VQ: z [16384,512] f32, emb [8192,512] f32
// outputs (flat f32): z_q [8388608], loss [1], idx [16384], var [1]

#define BT   16384
#define DIMS 512
#define NE   8192

#define TM 64
#define TN 128
#define TK 32

// ws layout (bytes)
#define ENORM_OFF  0         // float[8192]        -> 32768
#define CAND_S_OFF 32768     // float[32768]       -> +131072
#define CAND_I_OFF 163840    // int[32768]         -> +131072
#define SUMS_OFF   294912    // double[3]

// out layout (float elements)
#define LOSS_OFF 8388608
#define IDX_OFF  8388609
#define V_OFF    8404993

__global__ void init_sums(double* sums) {
    sums[0] = 0.0; sums[1] = 0.0; sums[2] = 0.0;
}

__global__ __launch_bounds__(256) void enorm_kernel(const float* __restrict__ emb,
                                                    float* __restrict__ enorm) {
    int lane = threadIdx.x & 63;
    int w = threadIdx.x >> 6;
    int code = blockIdx.x * 4 + w;
    const float4* p = (const float4*)(emb + (size_t)code * DIMS + lane * 8);
    float4 a = p[0], b = p[1];
    float s = a.x*a.x + a.y*a.y + a.z*a.z + a.w*a.w
            + b.x*b.x + b.y*b.y + b.z*b.z + b.w*b.w;
    #pragma unroll
    for (int off = 32; off > 0; off >>= 1) s += __shfl_down(s, off, 64);
    if (lane == 0) enorm[code] = s;
}

// Tiled GEMM-like argmin: score[m][n] = ||e_n||^2 - 2 * z_m . e_n
// (drops constant ||z_m||^2 to avoid fp32 cancellation against ~512)
__global__ __launch_bounds__(256) void argmin_kernel(
    const float* __restrict__ z, const float* __restrict__ emb,
    const float* __restrict__ enorm,
    float* __restrict__ cand_s, int* __restrict__ cand_i)
{
    __shared__ float As[TK][TM];   // 8 KB
    __shared__ float Bs[TK][TN];   // 16 KB
    const int t = threadIdx.x;
    const int split = blockIdx.x & 1;
    const int m0 = (blockIdx.x >> 1) * TM;
    const int tx = t & 15, ty = t >> 4;

    const int arow = t >> 2, akoff = (t & 3) * 8;   // A: 64 rows x 32 k, 8 floats/thread
    const int brow = t >> 1, bkoff = (t & 1) * 16;  // B: 128 rows x 32 k, 16 floats/thread

    const float* zA = z + (size_t)(m0 + arow) * DIMS + akoff;

    float best[4];
    int bidx[4];
    #pragma unroll
    for (int i = 0; i < 4; i++) { best[i] = 3.4e38f; bidx[i] = 0; }

    const int nbase0 = split * (NE / 2);
    for (int n0 = 0; n0 < NE / 2; n0 += TN) {
        const int nb = nbase0 + n0;
        float acc[4][8];
        #pragma unroll
        for (int i = 0; i < 4; i++)
            #pragma unroll
            for (int j = 0; j < 8; j++) acc[i][j] = 0.0f;

        const float* eB = emb + (size_t)(nb + brow) * DIMS + bkoff;

        for (int k0 = 0; k0 < DIMS; k0 += TK) {
            float4 a0 = *(const float4*)(zA + k0);
            float4 a1 = *(const float4*)(zA + k0 + 4);
            float4 b0 = *(const float4*)(eB + k0);
            float4 b1 = *(const float4*)(eB + k0 + 4);
            float4 b2 = *(const float4*)(eB + k0 + 8);
            float4 b3 = *(const float4*)(eB + k0 + 12);
            __syncthreads();
            As[akoff+0][arow] = a0.x; As[akoff+1][arow] = a0.y;
            As[akoff+2][arow] = a0.z; As[akoff+3][arow] = a0.w;
            As[akoff+4][arow] = a1.x; As[akoff+5][arow] = a1.y;
            As[akoff+6][arow] = a1.z; As[akoff+7][arow] = a1.w;
            Bs[bkoff+ 0][brow] = b0.x; Bs[bkoff+ 1][brow] = b0.y;
            Bs[bkoff+ 2][brow] = b0.z; Bs[bkoff+ 3][brow] = b0.w;
            Bs[bkoff+ 4][brow] = b1.x; Bs[bkoff+ 5][brow] = b1.y;
            Bs[bkoff+ 6][brow] = b1.z; Bs[bkoff+ 7][brow] = b1.w;
            Bs[bkoff+ 8][brow] = b2.x; Bs[bkoff+ 9][brow] = b2.y;
            Bs[bkoff+10][brow] = b2.z; Bs[bkoff+11][brow] = b2.w;
            Bs[bkoff+12][brow] = b3.x; Bs[bkoff+13][brow] = b3.y;
            Bs[bkoff+14][brow] = b3.z; Bs[bkoff+15][brow] = b3.w;
            __syncthreads();
            #pragma unroll
            for (int kk = 0; kk < TK; kk++) {
                float4 av  = *(const float4*)&As[kk][ty * 4];
                float4 bv0 = *(const float4*)&Bs[kk][tx * 8];
                float4 bv1 = *(const float4*)&Bs[kk][tx * 8 + 4];
                float a[4] = {av.x, av.y, av.z, av.w};
                float b[8] = {bv0.x, bv0.y, bv0.z, bv0.w, bv1.x, bv1.y, bv1.z, bv1.w};
                #pragma unroll
                for (int i = 0; i < 4; i++)
                    #pragma unroll
                    for (int j = 0; j < 8; j++)
                        acc[i][j] = fmaf(a[i], b[j], acc[i][j]);
            }
        }
        float4 en0 = *(const float4*)(enorm + nb + tx * 8);
        float4 en1 = *(const float4*)(enorm + nb + tx * 8 + 4);
        float en[8] = {en0.x, en0.y, en0.z, en0.w, en1.x, en1.y, en1.z, en1.w};
        #pragma unroll
        for (int j = 0; j < 8; j++) {   // j outer: codes ascending -> first-min kept
            int n = nb + tx * 8 + j;
            #pragma unroll
            for (int i = 0; i < 4; i++) {
                float s = fmaf(-2.0f, acc[i][j], en[j]);
                if (s < best[i]) { best[i] = s; bidx[i] = n; }
            }
        }
    }
    // cross-thread merge per row (16 tx-candidates per row), tie-break lower idx
    __syncthreads();
    float* sbuf = &As[0][0];      // 1024 floats needed, 2048 available
    int*   ibuf = (int*)&Bs[0][0];
    #pragma unroll
    for (int i = 0; i < 4; i++) {
        int r = ty * 4 + i;
        sbuf[r * 16 + tx] = best[i];
        ibuf[r * 16 + tx] = bidx[i];
    }
    __syncthreads();
    if (t < 64) {
        float bs = sbuf[t * 16];
        int bi = ibuf[t * 16];
        for (int x = 1; x < 16; x++) {
            float s = sbuf[t * 16 + x];
            int id = ibuf[t * 16 + x];
            if (s < bs || (s == bs && id < bi)) { bs = s; bi = id; }
        }
        int row = m0 + t;
        cand_s[(size_t)row * 2 + split] = bs;
        cand_i[(size_t)row * 2 + split] = bi;
    }
}

// one block per 64 rows: merge 2 split-candidates, gather z_q, loss + idx stats
__global__ __launch_bounds__(256) void gather_loss_kernel(
    const float* __restrict__ z, const float* __restrict__ emb,
    const float* __restrict__ cand_s, const int* __restrict__ cand_i,
    float* __restrict__ out, double* __restrict__ sums)
{
    __shared__ int sIdx[64];
    __shared__ double red[4];
    const int t = threadIdx.x;
    const int row0 = blockIdx.x * 64;
    double myIdxSum = 0.0, myIdxSq = 0.0;
    if (t < 64) {
        int row = row0 + t;
        float s0 = cand_s[2 * row], s1 = cand_s[2 * row + 1];
        int i0 = cand_i[2 * row], i1 = cand_i[2 * row + 1];
        int idx = (s1 < s0) ? i1 : i0;   // tie -> lower (split 0) index
        sIdx[t] = idx;
        out[IDX_OFF + row] = (float)idx;
        myIdxSum = (double)idx;
        myIdxSq = (double)idx * (double)idx;
    }
    __syncthreads();
    double acc = 0.0;
    #pragma unroll 4
    for (int i = 0; i < 32; i++) {
        int e = i * 1024 + t * 4;        // 64 rows x 512 = 32768 elems per block
        int rl = e >> 9;
        int c = e & 511;
        int idx = sIdx[rl];
        float4 zv = *(const float4*)(z + (size_t)(row0 + rl) * DIMS + c);
        float4 ev = *(const float4*)(emb + (size_t)idx * DIMS + c);
        *(float4*)(out + (size_t)(row0 + rl) * DIMS + c) = ev;  // z_q_st value == z_q
        float dx = zv.x - ev.x, dy = zv.y - ev.y;
        float dz = zv.z - ev.z, dw = zv.w - ev.w;
        acc += (double)(dx * dx + dy * dy) + (double)(dz * dz + dw * dw);
    }
    const int lane = t & 63, w = t >> 6;
    #pragma unroll
    for (int off = 32; off > 0; off >>= 1) {
        acc      += __shfl_down(acc, off, 64);
        myIdxSum += __shfl_down(myIdxSum, off, 64);
        myIdxSq  += __shfl_down(myIdxSq, off, 64);
    }
    if (lane == 0) red[w] = acc;
    __syncthreads();
    if (t == 0) {
        double tot = red[0] + red[1] + red[2] + red[3];
        atomicAdd(&sums[0], tot);
        atomicAdd(&sums[1], myIdxSum);   // only wave 0 held idx stats
        atomicAdd(&sums[2], myIdxSq);
    }
}

__global__ void finalize_kernel(const double* __restrict__ sums, float* __restrict__ out) {
    out[LOSS_OFF] = (float)(1.25 * sums[0] / (double)((size_t)BT * DIMS));
    double m = sums[1] / (double)BT;
    out[V_OFF] = (float)(sums[2] / (double)BT - m * m);
}

extern "C" void kernel_launch(void* const* d_in, const int* in_sizes, int n_in,
                              void* d_out, int out_size, void* d_ws, size_t ws_size,
                              hipStream_t stream) {
    const float* z = (const float*)d_in[0];
    const float* emb = (const float*)d_in[1];
    float* out = (float*)d_out;
    char* ws = (char*)d_ws;
    float* enorm  = (float*)(ws + ENORM_OFF);
    float* cand_s = (float*)(ws + CAND_S_OFF);
    int*   cand_i = (int*)(ws + CAND_I_OFF);
    double* sums  = (double*)(ws + SUMS_OFF);

    hipLaunchKernelGGL(init_sums, dim3(1), dim3(1), 0, stream, sums);
    hipLaunchKernelGGL(enorm_kernel, dim3(NE / 4), dim3(256), 0, stream, emb, enorm);
    hipLaunchKernelGGL(argmin_kernel, dim3((BT / TM) * 2), dim3(256), 0, stream,
                       z, emb, enorm, cand_s, cand_i);
    hipLaunchKernelGGL(gather_loss_kernel, dim3(BT / 64), dim3(256), 0, stream,
                       z, emb, cand_s, cand_i, out, sums);
    hipLaunchKernelGGL(finalize_kernel, dim3(1), dim3(1), 0, stream, sums, out);
}

// Round 2
// 310.367 us; speedup vs baseline: 6.1589x; 6.1589x over previous
//
#include <hip/hip_runtime.h>

// VQ: z [16384,512] f32, emb [8192,512] f32
// outputs (flat f32): z_q [8388608], loss [1], idx [16384], var [1]

#define BT   16384
#define DIMS 512
#define NE   8192

// out layout (float elements)
#define LOSS_OFF 8388608
#define IDX_OFF  8388609
#define V_OFF    8404993

// ws layout (bytes): best u64[16384] @0, enorm f32[8192] @131072, sums double[3] @163840
#define BEST_OFF  0
#define ENORM_OFF 131072
#define SUMS_OFF  163840

typedef __attribute__((ext_vector_type(8))) short short8;
typedef __attribute__((ext_vector_type(4))) float floatx4;

#define AS1(p) ((const __attribute__((address_space(1))) void*)(p))
#define AS3(p) ((__attribute__((address_space(3))) void*)(p))

__device__ __forceinline__ unsigned short f2bf(float f) {
    unsigned u = __builtin_bit_cast(unsigned, f);
    u += 0x7FFFu + ((u >> 16) & 1u);          // RNE
    return (unsigned short)(u >> 16);
}

__global__ __launch_bounds__(256) void init_kernel(unsigned long long* __restrict__ best,
                                                   double* __restrict__ sums) {
    int t = blockIdx.x * 256 + threadIdx.x;
    if (t < BT) best[t] = 0xFFFFFFFFFFFFFFFFULL;
    if (t == 0) { sums[0] = 0.0; sums[1] = 0.0; sums[2] = 0.0; }
}

// fp32 -> bf16 (RNE), 8 elements per thread
__global__ __launch_bounds__(256) void convert_kernel(const float* __restrict__ src,
                                                      ushort* __restrict__ dst) {
    int gid = blockIdx.x * 256 + threadIdx.x;
    const float4* s = (const float4*)src;
    float4 a = s[gid * 2], b = s[gid * 2 + 1];
    uint4 h;
    h.x = (unsigned)f2bf(a.x) | ((unsigned)f2bf(a.y) << 16);
    h.y = (unsigned)f2bf(a.z) | ((unsigned)f2bf(a.w) << 16);
    h.z = (unsigned)f2bf(b.x) | ((unsigned)f2bf(b.y) << 16);
    h.w = (unsigned)f2bf(b.z) | ((unsigned)f2bf(b.w) << 16);
    ((uint4*)dst)[gid] = h;
}

__global__ __launch_bounds__(256) void enorm_kernel(const float* __restrict__ emb,
                                                    float* __restrict__ enorm) {
    int lane = threadIdx.x & 63;
    int w = threadIdx.x >> 6;
    int code = blockIdx.x * 4 + w;
    const float4* p = (const float4*)(emb + (size_t)code * DIMS + lane * 8);
    float4 a = p[0], b = p[1];
    float s = a.x*a.x + a.y*a.y + a.z*a.z + a.w*a.w
            + b.x*b.x + b.y*b.y + b.z*b.z + b.w*b.w;
    #pragma unroll
    for (int off = 32; off > 0; off >>= 1) s += __shfl_down(s, off, 64);
    if (lane == 0) enorm[code] = s;
}

// bf16 MFMA argmin GEMM: score[m][n] = ||e_n||^2 - 2 * z_m . e_n
// 128x128 tile per block, BK=32, 16x16x32 bf16 MFMA, global_load_lds staging.
// argmin via packed (score,idx) u64 keys -> atomicMin (lex min = first-occurrence tie-break).
__global__ __launch_bounds__(256) void argmin_mfma(
    const ushort* __restrict__ zh, const ushort* __restrict__ eh,
    const float* __restrict__ enorm, unsigned long long* __restrict__ best)
{
    __shared__ __align__(16) ushort lds[2][128][32];   // 16 KB: A(z) tile, B(e) tile
    const int t = threadIdx.x;
    const int w = t >> 6, lane = t & 63;
    const int quad = lane >> 4, l15 = lane & 15;
    const int mt = blockIdx.x & 127, nt = blockIdx.x >> 7;
    const int m0 = mt * 128, n0 = nt * 128;
    const int wm = (w & 1) * 64, wn = (w >> 1) * 64;

    // staging: wave 0/1 -> A halves, wave 2/3 -> B halves (lane-ordered [row][k] layout)
    const int half = w & 1;
    const ushort* gbase = (w < 2) ? (zh + (size_t)(m0 + half * 64) * DIMS)
                                  : (eh + (size_t)(n0 + half * 64) * DIMS);
    ushort* lbase = (w < 2) ? &lds[0][half * 64][0] : &lds[1][half * 64][0];
    const int srow = lane >> 2;           // row within 16-row chunk
    const int skel = (lane & 3) * 8;      // k element offset (16B granules)

    floatx4 acc[4][4];
    #pragma unroll
    for (int i = 0; i < 4; i++)
        #pragma unroll
        for (int j = 0; j < 4; j++)
            acc[i][j] = (floatx4){0.f, 0.f, 0.f, 0.f};

    for (int k0 = 0; k0 < DIMS; k0 += 32) {
        __syncthreads();
        #pragma unroll
        for (int c = 0; c < 4; c++) {
            const ushort* g = gbase + (size_t)(c * 16 + srow) * DIMS + (k0 + skel);
            __builtin_amdgcn_global_load_lds(AS1(g), AS3(lbase + c * 512), 16, 0, 0);
        }
        __syncthreads();
        short8 a[4], b[4];
        #pragma unroll
        for (int i = 0; i < 4; i++)
            a[i] = *(const short8*)&lds[0][wm + i * 16 + l15][quad * 8];
        #pragma unroll
        for (int j = 0; j < 4; j++)
            b[j] = *(const short8*)&lds[1][wn + j * 16 + l15][quad * 8];
        #pragma unroll
        for (int i = 0; i < 4; i++)
            #pragma unroll
            for (int j = 0; j < 4; j++)
                acc[i][j] = __builtin_amdgcn_mfma_f32_16x16x32_bf16(a[i], b[j], acc[i][j], 0, 0, 0);
    }

    // epilogue: per-row min over this block's 128 codes, then global atomicMin
    float en[4]; int nn[4];
    #pragma unroll
    for (int j = 0; j < 4; j++) { nn[j] = n0 + wn + j * 16 + l15; en[j] = enorm[nn[j]]; }
    #pragma unroll
    for (int i = 0; i < 4; i++) {
        #pragma unroll
        for (int r = 0; r < 4; r++) {
            unsigned long long key = 0xFFFFFFFFFFFFFFFFULL;
            #pragma unroll
            for (int j = 0; j < 4; j++) {
                float s = fmaf(-2.0f, acc[i][j][r], en[j]);
                unsigned su = __builtin_bit_cast(unsigned, s);
                su = (su & 0x80000000u) ? ~su : (su | 0x80000000u);  // order-preserving map
                unsigned long long k2 = ((unsigned long long)su << 32) | (unsigned)nn[j];
                key = (k2 < key) ? k2 : key;
            }
            #pragma unroll
            for (int off = 1; off < 16; off <<= 1) {
                unsigned long long o = __shfl_xor(key, off, 64);
                key = (o < key) ? o : key;
            }
            if (l15 == 0) {
                int m = m0 + wm + i * 16 + quad * 4 + r;
                atomicMin(&best[m], key);
            }
        }
    }
}

// one block per 64 rows: read idx from packed keys, gather z_q, loss + idx stats
__global__ __launch_bounds__(256) void gather_loss_kernel(
    const float* __restrict__ z, const float* __restrict__ emb,
    const unsigned long long* __restrict__ best,
    float* __restrict__ out, double* __restrict__ sums)
{
    __shared__ int sIdx[64];
    __shared__ double red[4];
    const int t = threadIdx.x;
    const int row0 = blockIdx.x * 64;
    double myIdxSum = 0.0, myIdxSq = 0.0;
    if (t < 64) {
        int row = row0 + t;
        int idx = (int)(unsigned)(best[row] & 0xFFFFFFFFULL);
        sIdx[t] = idx;
        out[IDX_OFF + row] = (float)idx;
        myIdxSum = (double)idx;
        myIdxSq = (double)idx * (double)idx;
    }
    __syncthreads();
    double acc = 0.0;
    #pragma unroll 4
    for (int i = 0; i < 32; i++) {
        int e = i * 1024 + t * 4;        // 64 rows x 512 = 32768 elems per block
        int rl = e >> 9;
        int c = e & 511;
        int idx = sIdx[rl];
        float4 zv = *(const float4*)(z + (size_t)(row0 + rl) * DIMS + c);
        float4 ev = *(const float4*)(emb + (size_t)idx * DIMS + c);
        *(float4*)(out + (size_t)(row0 + rl) * DIMS + c) = ev;  // z_q_st value == z_q
        float dx = zv.x - ev.x, dy = zv.y - ev.y;
        float dz = zv.z - ev.z, dw = zv.w - ev.w;
        acc += (double)(dx * dx + dy * dy) + (double)(dz * dz + dw * dw);
    }
    const int lane = t & 63, wv = t >> 6;
    #pragma unroll
    for (int off = 32; off > 0; off >>= 1) {
        acc      += __shfl_down(acc, off, 64);
        myIdxSum += __shfl_down(myIdxSum, off, 64);
        myIdxSq  += __shfl_down(myIdxSq, off, 64);
    }
    if (lane == 0) red[wv] = acc;
    __syncthreads();
    if (t == 0) {
        double tot = red[0] + red[1] + red[2] + red[3];
        atomicAdd(&sums[0], tot);
        atomicAdd(&sums[1], myIdxSum);   // wave 0 held all idx stats
        atomicAdd(&sums[2], myIdxSq);
    }
}

__global__ void finalize_kernel(const double* __restrict__ sums, float* __restrict__ out) {
    out[LOSS_OFF] = (float)(1.25 * sums[0] / (double)((size_t)BT * DIMS));
    double m = sums[1] / (double)BT;
    out[V_OFF] = (float)(sums[2] / (double)BT - m * m);
}

extern "C" void kernel_launch(void* const* d_in, const int* in_sizes, int n_in,
                              void* d_out, int out_size, void* d_ws, size_t ws_size,
                              hipStream_t stream) {
    const float* z = (const float*)d_in[0];
    const float* emb = (const float*)d_in[1];
    float* out = (float*)d_out;
    char* ws = (char*)d_ws;
    unsigned long long* best = (unsigned long long*)(ws + BEST_OFF);
    float* enorm  = (float*)(ws + ENORM_OFF);
    double* sums  = (double*)(ws + SUMS_OFF);

    // bf16 scratch lives in the z_q region of out (fully overwritten by gather at the end):
    // z_hi: 8M ushorts @ byte 0..16MB, e_hi: 4M ushorts @ 16MB..24MB  (z_q region = 32MB)
    ushort* zh = (ushort*)out;
    ushort* ehh = zh + (size_t)BT * DIMS;

    hipLaunchKernelGGL(init_kernel, dim3(BT / 256), dim3(256), 0, stream, best, sums);
    hipLaunchKernelGGL(convert_kernel, dim3(BT * DIMS / 8 / 256), dim3(256), 0, stream, z, zh);
    hipLaunchKernelGGL(convert_kernel, dim3(NE * DIMS / 8 / 256), dim3(256), 0, stream, emb, ehh);
    hipLaunchKernelGGL(enorm_kernel, dim3(NE / 4), dim3(256), 0, stream, emb, enorm);
    hipLaunchKernelGGL(argmin_mfma, dim3((BT / 128) * (NE / 128)), dim3(256), 0, stream,
                       zh, ehh, enorm, best);
    hipLaunchKernelGGL(gather_loss_kernel, dim3(BT / 64), dim3(256), 0, stream,
                       z, emb, best, out, sums);
    hipLaunchKernelGGL(finalize_kernel, dim3(1), dim3(1), 0, stream, sums, out);
}

// Round 3
// 307.214 us; speedup vs baseline: 6.2221x; 1.0103x over previous
//
#include <hip/hip_runtime.h>

// VQ: z [16384,512] f32, emb [8192,512] f32
// outputs (flat f32): z_q [8388608], loss [1], idx [16384], var [1]

#define BT   16384
#define DIMS 512
#define NE   8192

// out layout (float elements)
#define LOSS_OFF 8388608
#define IDX_OFF  8388609
#define V_OFF    8404993

// ws layout (bytes)
#define BEST_OFF  0         // u64[16384]
#define ENORM_OFF 131072    // f32[8192]
#define SUMS_OFF  163840    // double[3]

typedef __attribute__((ext_vector_type(8))) short short8;
typedef __attribute__((ext_vector_type(4))) float floatx4;

#define AS1(p) ((const __attribute__((address_space(1))) void*)(p))
#define AS3(p) ((__attribute__((address_space(3))) void*)(p))

__device__ __forceinline__ unsigned f2bf(float f) {
    unsigned u = __builtin_bit_cast(unsigned, f);
    u += 0x7FFFu + ((u >> 16) & 1u);          // RNE
    return u >> 16;
}

// fused: emb fp32->bf16 convert + ||e||^2 + init best/sums. one wave per emb row.
__global__ __launch_bounds__(256) void emb_prep(const float* __restrict__ emb,
                                                ushort* __restrict__ ehh,
                                                float* __restrict__ enorm,
                                                unsigned long long* __restrict__ best,
                                                double* __restrict__ sums) {
    const int lane = threadIdx.x & 63, w = threadIdx.x >> 6;
    const int row = blockIdx.x * 4 + w;
    const float4* p = (const float4*)(emb + (size_t)row * DIMS + lane * 8);
    float4 a = p[0], b = p[1];
    uint4 h;
    h.x = f2bf(a.x) | (f2bf(a.y) << 16);
    h.y = f2bf(a.z) | (f2bf(a.w) << 16);
    h.z = f2bf(b.x) | (f2bf(b.y) << 16);
    h.w = f2bf(b.z) | (f2bf(b.w) << 16);
    *(uint4*)(ehh + (size_t)row * DIMS + lane * 8) = h;
    float s = a.x*a.x + a.y*a.y + a.z*a.z + a.w*a.w
            + b.x*b.x + b.y*b.y + b.z*b.z + b.w*b.w;
    #pragma unroll
    for (int off = 32; off > 0; off >>= 1) s += __shfl_down(s, off, 64);
    if (lane == 0) enorm[row] = s;
    const int gid = blockIdx.x * 256 + threadIdx.x;
    if (gid < BT) best[gid] = 0xFFFFFFFFFFFFFFFFULL;
    if (gid == 0) { sums[0] = 0.0; sums[1] = 0.0; sums[2] = 0.0; }
}

// fp32 -> bf16 (RNE), 8 elements per thread
__global__ __launch_bounds__(256) void convert_kernel(const float* __restrict__ src,
                                                      ushort* __restrict__ dst) {
    const int gid = blockIdx.x * 256 + threadIdx.x;
    const float4* s = (const float4*)src;
    float4 a = s[gid * 2], b = s[gid * 2 + 1];
    uint4 h;
    h.x = f2bf(a.x) | (f2bf(a.y) << 16);
    h.y = f2bf(a.z) | (f2bf(a.w) << 16);
    h.z = f2bf(b.x) | (f2bf(b.y) << 16);
    h.w = f2bf(b.z) | (f2bf(b.w) << 16);
    ((uint4*)dst)[gid] = h;
}

// bf16 MFMA argmin GEMM: score[m][n] = ||e_n||^2 - 2 * z_m . e_n
// 128x128 tile, BK=64, 16x16x32 MFMA, global_load_lds staging with XOR-swizzled
// k-chunks (chunk' = chunk ^ (row&7)) so frag ds_read_b128 is 2-way (free) instead
// of 4-8-way conflicted. argmin via packed (score,idx) u64 -> atomicMin
// (lex min = numpy first-occurrence tie-break).
__global__ __launch_bounds__(256) void argmin_mfma(
    const ushort* __restrict__ zh, const ushort* __restrict__ eh,
    const float* __restrict__ enorm, unsigned long long* __restrict__ best)
{
    __shared__ __align__(16) ushort lds[2][128][64];   // 32 KB: A(z), B(e)
    const int t = threadIdx.x;
    const int w = t >> 6, lane = t & 63;
    const int quad = lane >> 4, l15 = lane & 15;
    const int mt = blockIdx.x & 127, nt = blockIdx.x >> 7;
    const int m0 = mt * 128, n0 = nt * 128;
    const int wm = (w & 1) * 64, wn = (w >> 1) * 64;

    // staging: waves 0/1 -> A halves, 2/3 -> B halves.
    // lane l writes physical 16B chunk (l&7) of row (c*8 + (l>>3)); the logical
    // k-chunk loaded there is (l&7) ^ (row&7)  [row&7 == (l>>3)&7].
    const int half = w & 1;
    const int tile = (w < 2) ? 0 : 1;
    const ushort* gbase = (w < 2) ? (zh + (size_t)m0 * DIMS) : (eh + (size_t)n0 * DIMS);
    const int srow = half * 64 + (lane >> 3);           // + c*8 below
    const int lchunk = (lane & 7) ^ ((lane >> 3) & 7);  // logical chunk this lane fetches
    ushort* lb0 = &lds[tile][half * 64][0];

    // frag-read physical chunk for kk=0/1: (kk*4+quad) ^ (row&7), row&7 == l15&7
    const int px0 = quad ^ (l15 & 7);
    const int px1 = (4 + quad) ^ (l15 & 7);

    floatx4 acc[4][4];
    #pragma unroll
    for (int i = 0; i < 4; i++)
        #pragma unroll
        for (int j = 0; j < 4; j++)
            acc[i][j] = (floatx4){0.f, 0.f, 0.f, 0.f};

    for (int k0 = 0; k0 < DIMS; k0 += 64) {
        __syncthreads();
        #pragma unroll
        for (int c = 0; c < 8; c++) {
            const ushort* g = gbase + (size_t)(srow + c * 8) * DIMS + (k0 + lchunk * 8);
            __builtin_amdgcn_global_load_lds(AS1(g), AS3(lb0 + c * 512), 16, 0, 0);
        }
        __syncthreads();
        #pragma unroll
        for (int kk = 0; kk < 2; kk++) {
            const int px = kk ? px1 : px0;
            short8 a[4], b[4];
            #pragma unroll
            for (int i = 0; i < 4; i++)
                a[i] = *(const short8*)&lds[0][wm + i * 16 + l15][px * 8];
            #pragma unroll
            for (int j = 0; j < 4; j++)
                b[j] = *(const short8*)&lds[1][wn + j * 16 + l15][px * 8];
            #pragma unroll
            for (int i = 0; i < 4; i++)
                #pragma unroll
                for (int j = 0; j < 4; j++)
                    acc[i][j] = __builtin_amdgcn_mfma_f32_16x16x32_bf16(a[i], b[j], acc[i][j], 0, 0, 0);
        }
    }

    // epilogue: fp32 j-reduction w/ index tracking, single u64 pack, shfl-min over l15
    float en[4]; int nn[4];
    #pragma unroll
    for (int j = 0; j < 4; j++) { nn[j] = n0 + wn + j * 16 + l15; en[j] = enorm[nn[j]]; }
    #pragma unroll
    for (int i = 0; i < 4; i++) {
        const int rowm = m0 + wm + i * 16 + quad * 4;
        #pragma unroll
        for (int r = 0; r < 4; r++) {
            float bs = 3.4e38f; int bn = 0;
            #pragma unroll
            for (int j = 0; j < 4; j++) {   // ascending n -> strict < keeps first min
                float s = fmaf(-2.0f, acc[i][j][r], en[j]);
                if (s < bs) { bs = s; bn = nn[j]; }
            }
            unsigned su = __builtin_bit_cast(unsigned, bs);
            su = (su & 0x80000000u) ? ~su : (su | 0x80000000u);  // order-preserving
            unsigned long long key = ((unsigned long long)su << 32) | (unsigned)bn;
            #pragma unroll
            for (int off = 1; off < 16; off <<= 1) {
                unsigned long long o = __shfl_xor(key, off, 64);
                key = (o < key) ? o : key;
            }
            if (l15 == 0) atomicMin(&best[rowm + r], key);
        }
    }
}

// one block per 64 rows: read idx from packed keys, gather z_q, loss + idx stats
__global__ __launch_bounds__(256) void gather_loss_kernel(
    const float* __restrict__ z, const float* __restrict__ emb,
    const unsigned long long* __restrict__ best,
    float* __restrict__ out, double* __restrict__ sums)
{
    __shared__ int sIdx[64];
    __shared__ double red[4];
    const int t = threadIdx.x;
    const int row0 = blockIdx.x * 64;
    double myIdxSum = 0.0, myIdxSq = 0.0;
    if (t < 64) {
        int row = row0 + t;
        int idx = (int)(unsigned)(best[row] & 0xFFFFFFFFULL);
        sIdx[t] = idx;
        out[IDX_OFF + row] = (float)idx;
        myIdxSum = (double)idx;
        myIdxSq = (double)idx * (double)idx;
    }
    __syncthreads();
    double acc = 0.0;
    #pragma unroll 4
    for (int i = 0; i < 32; i++) {
        int e = i * 1024 + t * 4;        // 64 rows x 512 = 32768 elems per block
        int rl = e >> 9;
        int c = e & 511;
        int idx = sIdx[rl];
        float4 zv = *(const float4*)(z + (size_t)(row0 + rl) * DIMS + c);
        float4 ev = *(const float4*)(emb + (size_t)idx * DIMS + c);
        *(float4*)(out + (size_t)(row0 + rl) * DIMS + c) = ev;  // z_q_st value == z_q
        float dx = zv.x - ev.x, dy = zv.y - ev.y;
        float dz = zv.z - ev.z, dw = zv.w - ev.w;
        acc += (double)(dx * dx + dy * dy) + (double)(dz * dz + dw * dw);
    }
    const int lane = t & 63, wv = t >> 6;
    #pragma unroll
    for (int off = 32; off > 0; off >>= 1) {
        acc      += __shfl_down(acc, off, 64);
        myIdxSum += __shfl_down(myIdxSum, off, 64);
        myIdxSq  += __shfl_down(myIdxSq, off, 64);
    }
    if (lane == 0) red[wv] = acc;
    __syncthreads();
    if (t == 0) {
        double tot = red[0] + red[1] + red[2] + red[3];
        atomicAdd(&sums[0], tot);
        atomicAdd(&sums[1], myIdxSum);   // wave 0 held all idx stats
        atomicAdd(&sums[2], myIdxSq);
    }
}

__global__ void finalize_kernel(const double* __restrict__ sums, float* __restrict__ out) {
    out[LOSS_OFF] = (float)(1.25 * sums[0] / (double)((size_t)BT * DIMS));
    double m = sums[1] / (double)BT;
    out[V_OFF] = (float)(sums[2] / (double)BT - m * m);
}

extern "C" void kernel_launch(void* const* d_in, const int* in_sizes, int n_in,
                              void* d_out, int out_size, void* d_ws, size_t ws_size,
                              hipStream_t stream) {
    const float* z = (const float*)d_in[0];
    const float* emb = (const float*)d_in[1];
    float* out = (float*)d_out;
    char* ws = (char*)d_ws;
    unsigned long long* best = (unsigned long long*)(ws + BEST_OFF);
    float* enorm  = (float*)(ws + ENORM_OFF);
    double* sums  = (double*)(ws + SUMS_OFF);

    // bf16 scratch in the z_q region of out (fully overwritten by gather at the end):
    // z_hi: 16 MB @0, e_hi: 8 MB @16MB (z_q region = 32 MB)
    ushort* zh = (ushort*)out;
    ushort* ehh = zh + (size_t)BT * DIMS;

    hipLaunchKernelGGL(emb_prep, dim3(NE / 4), dim3(256), 0, stream, emb, ehh, enorm, best, sums);
    hipLaunchKernelGGL(convert_kernel, dim3(BT * DIMS / 8 / 256), dim3(256), 0, stream, z, zh);
    hipLaunchKernelGGL(argmin_mfma, dim3((BT / 128) * (NE / 128)), dim3(256), 0, stream,
                       zh, ehh, enorm, best);
    hipLaunchKernelGGL(gather_loss_kernel, dim3(BT / 64), dim3(256), 0, stream,
                       z, emb, best, out, sums);
    hipLaunchKernelGGL(finalize_kernel, dim3(1), dim3(1), 0, stream, sums, out);
}

// Round 4
// 289.603 us; speedup vs baseline: 6.6005x; 1.0608x over previous
//
#include <hip/hip_runtime.h>

// VQ: z [16384,512] f32, emb [8192,512] f32
// outputs (flat f32): z_q [8388608], loss [1], idx [16384], var [1]

#define BT   16384
#define DIMS 512
#define NE   8192
#define NSPLIT 8
#define NTPB (NE / NSPLIT / 128)   // n-tiles per block = 8

// out layout (float elements)
#define LOSS_OFF 8388608
#define IDX_OFF  8388609
#define V_OFF    8404993

// ws layout (bytes)
#define BEST_OFF  0         // u64[16384]
#define ENORM_OFF 131072    // f32[8192]
#define SUMS_OFF  163840    // double[3]
#define CNT_OFF   163864    // unsigned

typedef __attribute__((ext_vector_type(8))) short short8;
typedef __attribute__((ext_vector_type(4))) float floatx4;

#define AS1(p) ((const __attribute__((address_space(1))) void*)(p))
#define AS3(p) ((__attribute__((address_space(3))) void*)(p))

__device__ __forceinline__ unsigned f2bf(float f) {
    unsigned u = __builtin_bit_cast(unsigned, f);
    u += 0x7FFFu + ((u >> 16) & 1u);          // RNE
    return u >> 16;
}

// fused prep: emb->bf16 + ||e||^2 (blocks 0..NE/4), z->bf16 (rest), init best/sums/counter
__global__ __launch_bounds__(256) void prep_kernel(
    const float* __restrict__ z, const float* __restrict__ emb,
    ushort* __restrict__ zh, ushort* __restrict__ ehh,
    float* __restrict__ enorm, unsigned long long* __restrict__ best,
    double* __restrict__ sums, unsigned* __restrict__ counter)
{
    const int lane = threadIdx.x & 63, w = threadIdx.x >> 6;
    const int b = blockIdx.x;
    if (b < NE / 4) {
        const int row = b * 4 + w;
        const float4* p = (const float4*)(emb + (size_t)row * DIMS + lane * 8);
        float4 a = p[0], bb = p[1];
        uint4 h;
        h.x = f2bf(a.x) | (f2bf(a.y) << 16);
        h.y = f2bf(a.z) | (f2bf(a.w) << 16);
        h.z = f2bf(bb.x) | (f2bf(bb.y) << 16);
        h.w = f2bf(bb.z) | (f2bf(bb.w) << 16);
        *(uint4*)(ehh + (size_t)row * DIMS + lane * 8) = h;
        float s = a.x*a.x + a.y*a.y + a.z*a.z + a.w*a.w
                + bb.x*bb.x + bb.y*bb.y + bb.z*bb.z + bb.w*bb.w;
        #pragma unroll
        for (int off = 32; off > 0; off >>= 1) s += __shfl_down(s, off, 64);
        if (lane == 0) enorm[row] = s;
    } else {
        const int row = (b - NE / 4) * 4 + w;
        const float4* p = (const float4*)(z + (size_t)row * DIMS + lane * 8);
        float4 a = p[0], bb = p[1];
        uint4 h;
        h.x = f2bf(a.x) | (f2bf(a.y) << 16);
        h.y = f2bf(a.z) | (f2bf(a.w) << 16);
        h.z = f2bf(bb.x) | (f2bf(bb.y) << 16);
        h.w = f2bf(bb.z) | (f2bf(bb.w) << 16);
        *(uint4*)(zh + (size_t)row * DIMS + lane * 8) = h;
    }
    const int gid = b * 256 + threadIdx.x;
    if (gid < BT) best[gid] = 0xFFFFFFFFFFFFFFFFULL;
    if (gid == 0) { sums[0] = 0.0; sums[1] = 0.0; sums[2] = 0.0; *counter = 0u; }
}

// bf16 MFMA argmin: score[m][n] = ||e_n||^2 - 2 z_m.e_n.  128x128 tiles, BK=64,
// 16x16x32 MFMA, XOR-swizzled global_load_lds staging (conflict-free frag reads).
// Each block sweeps 8 n-tiles keeping running (best,idx) in registers; the
// pack/shfl/atomicMin epilogue runs once per block. Ascending-n strict-< =
// numpy first-occurrence tie-break.
__global__ __launch_bounds__(256) void argmin_mfma(
    const ushort* __restrict__ zh, const ushort* __restrict__ eh,
    const float* __restrict__ enorm, unsigned long long* __restrict__ best)
{
    __shared__ __align__(16) ushort lds[2][128][64];   // 32 KB
    const int t = threadIdx.x;
    const int w = t >> 6, lane = t & 63;
    const int quad = lane >> 4, l15 = lane & 15;
    const int mt = blockIdx.x & 127, ns = blockIdx.x >> 7;
    const int m0 = mt * 128;
    const int wm = (w & 1) * 64, wn = (w >> 1) * 64;

    // staging: waves 0/1 -> A halves, 2/3 -> B halves.
    // lane l writes physical 16B chunk (l&7) of row (c*8 + (l>>3)); logical
    // k-chunk there is (l&7) ^ (row&7).
    const int half = w & 1;
    const int tile = (w < 2) ? 0 : 1;
    const int srow = half * 64 + (lane >> 3);
    const int lchunk = (lane & 7) ^ ((lane >> 3) & 7);
    ushort* lb0 = &lds[tile][half * 64][0];
    const ushort* zA = zh + (size_t)m0 * DIMS;

    // frag-read physical chunk for kk=0/1: (kk*4+quad) ^ (row&7), row&7 == l15&7
    const int px0 = quad ^ (l15 & 7);
    const int px1 = (4 + quad) ^ (l15 & 7);

    float bs[16];
    int   bn[16];
    #pragma unroll
    for (int k = 0; k < 16; k++) { bs[k] = 3.4e38f; bn[k] = 0; }

    for (int nt = 0; nt < NTPB; nt++) {
        const int n0 = (ns * NTPB + nt) * 128;
        const ushort* gbase = (w < 2) ? zA : (eh + (size_t)n0 * DIMS);

        floatx4 acc[4][4];
        #pragma unroll
        for (int i = 0; i < 4; i++)
            #pragma unroll
            for (int j = 0; j < 4; j++)
                acc[i][j] = (floatx4){0.f, 0.f, 0.f, 0.f};

        for (int k0 = 0; k0 < DIMS; k0 += 64) {
            __syncthreads();
            #pragma unroll
            for (int c = 0; c < 8; c++) {
                const ushort* g = gbase + (size_t)(srow + c * 8) * DIMS + (k0 + lchunk * 8);
                __builtin_amdgcn_global_load_lds(AS1(g), AS3(lb0 + c * 512), 16, 0, 0);
            }
            __syncthreads();
            #pragma unroll
            for (int kk = 0; kk < 2; kk++) {
                const int px = kk ? px1 : px0;
                short8 a[4], b[4];
                #pragma unroll
                for (int i = 0; i < 4; i++)
                    a[i] = *(const short8*)&lds[0][wm + i * 16 + l15][px * 8];
                #pragma unroll
                for (int j = 0; j < 4; j++)
                    b[j] = *(const short8*)&lds[1][wn + j * 16 + l15][px * 8];
                #pragma unroll
                for (int i = 0; i < 4; i++)
                    #pragma unroll
                    for (int j = 0; j < 4; j++)
                        acc[i][j] = __builtin_amdgcn_mfma_f32_16x16x32_bf16(a[i], b[j], acc[i][j], 0, 0, 0);
            }
        }

        // running best update (cheap: fma + cmp + 2 cndmask per (i,r,j))
        #pragma unroll
        for (int j = 0; j < 4; j++) {
            const int n = n0 + wn + j * 16 + l15;
            const float en = enorm[n];
            #pragma unroll
            for (int i = 0; i < 4; i++)
                #pragma unroll
                for (int r = 0; r < 4; r++) {
                    const int k = i * 4 + r;
                    float s = fmaf(-2.0f, acc[i][j][r], en);
                    if (s < bs[k]) { bs[k] = s; bn[k] = n; }
                }
        }
    }

    // once per block: pack, shfl-min over l15, atomicMin across the 8 n-splits
    #pragma unroll
    for (int i = 0; i < 4; i++)
        #pragma unroll
        for (int r = 0; r < 4; r++) {
            const int k = i * 4 + r;
            unsigned su = __builtin_bit_cast(unsigned, bs[k]);
            su = (su & 0x80000000u) ? ~su : (su | 0x80000000u);  // order-preserving
            unsigned long long key = ((unsigned long long)su << 32) | (unsigned)bn[k];
            #pragma unroll
            for (int off = 1; off < 16; off <<= 1) {
                unsigned long long o = __shfl_xor(key, off, 64);
                key = (o < key) ? o : key;
            }
            if (l15 == 0) atomicMin(&best[m0 + wm + i * 16 + quad * 4 + r], key);
        }
}

// one block per 64 rows: idx from packed keys, gather z_q, loss + idx stats;
// last block to finish runs the finalize.
__global__ __launch_bounds__(256) void gather_loss_kernel(
    const float* __restrict__ z, const float* __restrict__ emb,
    const unsigned long long* __restrict__ best,
    float* __restrict__ out, double* __restrict__ sums, unsigned* __restrict__ counter)
{
    __shared__ int sIdx[64];
    __shared__ double red[4];
    const int t = threadIdx.x;
    const int row0 = blockIdx.x * 64;
    double myIdxSum = 0.0, myIdxSq = 0.0;
    if (t < 64) {
        int row = row0 + t;
        int idx = (int)(unsigned)(best[row] & 0xFFFFFFFFULL);
        sIdx[t] = idx;
        out[IDX_OFF + row] = (float)idx;
        myIdxSum = (double)idx;
        myIdxSq = (double)idx * (double)idx;
    }
    __syncthreads();
    double acc = 0.0;
    #pragma unroll 4
    for (int i = 0; i < 32; i++) {
        int e = i * 1024 + t * 4;        // 64 rows x 512 = 32768 elems per block
        int rl = e >> 9;
        int c = e & 511;
        int idx = sIdx[rl];
        float4 zv = *(const float4*)(z + (size_t)(row0 + rl) * DIMS + c);
        float4 ev = *(const float4*)(emb + (size_t)idx * DIMS + c);
        *(float4*)(out + (size_t)(row0 + rl) * DIMS + c) = ev;  // z_q_st value == z_q
        float dx = zv.x - ev.x, dy = zv.y - ev.y;
        float dz = zv.z - ev.z, dw = zv.w - ev.w;
        acc += (double)(dx * dx + dy * dy) + (double)(dz * dz + dw * dw);
    }
    const int lane = t & 63, wv = t >> 6;
    #pragma unroll
    for (int off = 32; off > 0; off >>= 1) {
        acc      += __shfl_down(acc, off, 64);
        myIdxSum += __shfl_down(myIdxSum, off, 64);
        myIdxSq  += __shfl_down(myIdxSq, off, 64);
    }
    if (lane == 0) red[wv] = acc;
    __syncthreads();
    if (t == 0) {
        double tot = red[0] + red[1] + red[2] + red[3];
        atomicAdd(&sums[0], tot);
        atomicAdd(&sums[1], myIdxSum);   // wave 0 held all idx stats
        atomicAdd(&sums[2], myIdxSq);
        __threadfence();
        unsigned old = atomicAdd(counter, 1u);
        if (old == gridDim.x - 1) {
            __threadfence();
            double s0 = atomicAdd(&sums[0], 0.0);
            double s1 = atomicAdd(&sums[1], 0.0);
            double s2 = atomicAdd(&sums[2], 0.0);
            out[LOSS_OFF] = (float)(1.25 * s0 / (double)((size_t)BT * DIMS));
            double m = s1 / (double)BT;
            out[V_OFF] = (float)(s2 / (double)BT - m * m);
        }
    }
}

extern "C" void kernel_launch(void* const* d_in, const int* in_sizes, int n_in,
                              void* d_out, int out_size, void* d_ws, size_t ws_size,
                              hipStream_t stream) {
    const float* z = (const float*)d_in[0];
    const float* emb = (const float*)d_in[1];
    float* out = (float*)d_out;
    char* ws = (char*)d_ws;
    unsigned long long* best = (unsigned long long*)(ws + BEST_OFF);
    float* enorm  = (float*)(ws + ENORM_OFF);
    double* sums  = (double*)(ws + SUMS_OFF);
    unsigned* counter = (unsigned*)(ws + CNT_OFF);

    // bf16 scratch in the z_q region of out (fully overwritten by gather at the end)
    ushort* zh = (ushort*)out;
    ushort* ehh = zh + (size_t)BT * DIMS;

    hipLaunchKernelGGL(prep_kernel, dim3(NE / 4 + BT / 4), dim3(256), 0, stream,
                       z, emb, zh, ehh, enorm, best, sums, counter);
    hipLaunchKernelGGL(argmin_mfma, dim3(128 * NSPLIT), dim3(256), 0, stream,
                       zh, ehh, enorm, best);
    hipLaunchKernelGGL(gather_loss_kernel, dim3(BT / 64), dim3(256), 0, stream,
                       z, emb, best, out, sums, counter);
}